// Round 5
// baseline (272.041 us; speedup 1.0000x reference)
//
#include <hip/hip_runtime.h>

#define B_SZ 4
#define IN_CH 64
#define OUT_CH 128
#define NHI 163842
#define NLO 40962
#define EPS_GN 1e-5f
#define SLOPE 0.2f

typedef __attribute__((ext_vector_type(8))) short short8;
typedef __attribute__((ext_vector_type(16))) float f32x16;

__device__ inline ushort f2bf(float f) {
    union { float f; unsigned u; } v; v.f = f;
    unsigned r = v.u + 0x7FFF + ((v.u >> 16) & 1);
    return (ushort)(r >> 16);
}
__device__ inline float bf2f(ushort h) {
    union { unsigned u; float f; } v; v.u = ((unsigned)h) << 16;
    return v.f;
}

// async global->LDS, 16B per lane; LDS dest = uniform base + lane*16
__device__ inline void glds16(const ushort* g, ushort* l) {
    typedef __attribute__((address_space(1))) const void gv;
    typedef __attribute__((address_space(3))) void lv;
    __builtin_amdgcn_global_load_lds((gv*)g, (lv*)l, 16, 0, 0);
}

// ---------------------------------------------------------------------------
// 1) Transpose x: (B,64,NHI) f32 -> xT (B,NHI,64) bf16
// ---------------------------------------------------------------------------
__global__ void k_transpose_x(const float* __restrict__ x, ushort* __restrict__ xT) {
    __shared__ float t[64][65];
    const int b   = blockIdx.y;
    const int n0  = blockIdx.x * 64;
    const int tid = threadIdx.x;
    const int nq  = tid & 15;
    const int c0  = tid >> 4;
    const bool full = (n0 + 64) <= NHI;
    if (full) {
#pragma unroll
        for (int r = 0; r < 4; ++r) {
            int c = c0 + r * 16;
            float4 v = *(const float4*)&x[((long)b * IN_CH + c) * NHI + n0 + nq * 4];
            t[c][nq * 4 + 0] = v.x; t[c][nq * 4 + 1] = v.y;
            t[c][nq * 4 + 2] = v.z; t[c][nq * 4 + 3] = v.w;
        }
    } else {
        for (int r = 0; r < 4; ++r) {
            int c = c0 + r * 16;
            for (int e = 0; e < 4; ++e) {
                int n = n0 + nq * 4 + e;
                t[c][nq * 4 + e] = (n < NHI) ? x[((long)b * IN_CH + c) * NHI + n] : 0.f;
            }
        }
    }
    __syncthreads();
    const int n  = tid >> 2;
    const int cc = (tid & 3) * 16;
    if (n0 + n < NHI) {
        short8 o0, o1;
#pragma unroll
        for (int e = 0; e < 8; ++e) {
            o0[e] = (short)f2bf(t[cc + e][n]);
            o1[e] = (short)f2bf(t[cc + 8 + e][n]);
        }
        ushort* p = &xT[((long)b * NHI + n0 + n) * 64 + cc];
        *(short8*)p = o0;
        *(short8*)(p + 8) = o1;
    }
}

// ---------------------------------------------------------------------------
// 2) Pre-tile weights W (O=128, K) f32 -> Wb bf16:
//    Wb[step][kg(8)][o(128)][e(8)],  k = step*64 + kg*8 + e
// ---------------------------------------------------------------------------
__global__ void k_prep_w(const float* __restrict__ W, ushort* __restrict__ Wb, int K) {
    int i = blockIdx.x * 256 + threadIdx.x;
    if (i >= K * 128) return;
    int k = i / 128, o = i % 128;
    int step = k >> 6, kk = k & 63, kg = kk >> 3, e = kk & 7;
    Wb[(((long)(step * 8 + kg) * 128 + o) * 8) + e] = f2bf(W[(long)o * K + k]);
}

// ---------------------------------------------------------------------------
// 3) Mean pool
// ---------------------------------------------------------------------------
__global__ void k_pool(const ushort* __restrict__ xT, const int* __restrict__ pn,
                       ushort* __restrict__ h1) {
    long t = (long)blockIdx.x * 256 + threadIdx.x;
    const long total = (long)B_SZ * NLO * 8;
    if (t >= total) return;
    int  cq = (int)(t & 7);
    long bn = t >> 3;
    int  n  = (int)(bn % NLO);
    int  b  = (int)(bn / NLO);
    float acc[8] = {};
#pragma unroll
    for (int j = 0; j < 7; ++j) {
        int idx = pn[n * 7 + j];
        short8 v = *(const short8*)&xT[((long)b * NHI + idx) * 64 + cq * 8];
#pragma unroll
        for (int e = 0; e < 8; ++e) acc[e] += bf2f((ushort)v[e]);
    }
    short8 o;
#pragma unroll
    for (int e = 0; e < 8; ++e) o[e] = (short)f2bf(acc[e] * (1.f / 7.f));
    *(short8*)&h1[bn * 64 + cq * 8] = o;
}

// ---------------------------------------------------------------------------
// 4) MFMA one-ring conv, A-direct-from-global.
//    Block: 256 nodes x 128 outs, 4 waves, each 64 nodes x 128 outs.
//    A fragments gathered straight into VGPRs (no LDS); B (weights) staged
//    via global_load_lds, double-buffered, one barrier per K-step.
//    Per kh: 2 A-frags(global) + 4 B ds_reads -> 8 MFMAs (0.5 reads/MFMA).
// ---------------------------------------------------------------------------
template <int CIN>
__global__ __launch_bounds__(256, 2)
void k_conv_mfma(const ushort* __restrict__ src, const int* __restrict__ nbr,
                 const ushort* __restrict__ Wb, const float* __restrict__ bias,
                 ushort* __restrict__ out, float* __restrict__ part) {
    constexpr int NSTEP = 7 * CIN / 64;
    __shared__ ushort Bsm[2][8192];     // [kg(8)][o(128)][e(8)] per buffer, 16KB
    __shared__ float  red[4][4][2];

    const int b     = blockIdx.y;
    const int n0    = blockIdx.x * 256;
    const int tid   = threadIdx.x;
    const int lane  = tid & 63;
    const int wid   = tid >> 6;          // 0..3
    const int l31   = lane & 31;
    const int khalf = lane >> 5;

    // neighbor indices for this lane's two node rows
    const int rr0 = min(n0 + wid * 64 + l31, NLO - 1);
    const int rr1 = min(n0 + wid * 64 + 32 + l31, NLO - 1);
    int nb0[7], nb1[7];
#pragma unroll
    for (int j = 0; j < 7; ++j) {
        nb0[j] = nbr[rr0 * 7 + j];
        nb1[j] = nbr[rr1 * 7 + j];
    }

    const long srcb = (long)b * NLO * CIN;
    const int  koff = khalf * 8;

    f32x16 acc[2][4] = {};
    short8 a[2][4], an[2][4];

    // prologue: B step0 -> Bsm[0] via async DMA; A step0 -> regs
#pragma unroll
    for (int i = 0; i < 4; ++i) {
        int off = (wid * 4 + i) * 512;   // ushort offset, 1KB chunks per call
        glds16(&Wb[off + lane * 8], &Bsm[0][off]);
    }
    {
        const ushort* s0 = &src[srcb + (long)nb0[0] * CIN + koff];
        const ushort* s1 = &src[srcb + (long)nb1[0] * CIN + koff];
#pragma unroll
        for (int kh = 0; kh < 4; ++kh) {
            a[0][kh] = *(const short8*)(s0 + kh * 16);
            a[1][kh] = *(const short8*)(s1 + kh * 16);
        }
    }

#pragma unroll
    for (int step = 0; step < NSTEP; ++step) {
        const int cur = step & 1;
        __syncthreads();   // drains glds(step)->Bsm[cur] and orders prev reads
        if (step + 1 < NSTEP) {
            // async-stage next B into the other buffer (in flight across kh loop)
#pragma unroll
            for (int i = 0; i < 4; ++i) {
                int off = (wid * 4 + i) * 512;
                glds16(&Wb[(long)(step + 1) * 8192 + off + lane * 8], &Bsm[cur ^ 1][off]);
            }
            // prefetch next A fragments
            const int j2 = (CIN == 64) ? (step + 1) : ((step + 1) >> 1);
            const int cb2 = (CIN == 64) ? 0 : (((step + 1) & 1) * 64);
            const ushort* s0 = &src[srcb + (long)nb0[j2] * CIN + cb2 + koff];
            const ushort* s1 = &src[srcb + (long)nb1[j2] * CIN + cb2 + koff];
#pragma unroll
            for (int kh = 0; kh < 4; ++kh) {
                an[0][kh] = *(const short8*)(s0 + kh * 16);
                an[1][kh] = *(const short8*)(s1 + kh * 16);
            }
        }
#pragma unroll
        for (int kh = 0; kh < 4; ++kh) {
            const int kg = 2 * kh + khalf;
            const ushort* bb = &Bsm[cur][(kg * 128 + l31) * 8];
            short8 b0 = *(const short8*)(bb);
            short8 b1 = *(const short8*)(bb + 32 * 8);
            short8 b2 = *(const short8*)(bb + 64 * 8);
            short8 b3 = *(const short8*)(bb + 96 * 8);
            acc[0][0] = __builtin_amdgcn_mfma_f32_32x32x16_bf16(a[0][kh], b0, acc[0][0], 0, 0, 0);
            acc[0][1] = __builtin_amdgcn_mfma_f32_32x32x16_bf16(a[0][kh], b1, acc[0][1], 0, 0, 0);
            acc[0][2] = __builtin_amdgcn_mfma_f32_32x32x16_bf16(a[0][kh], b2, acc[0][2], 0, 0, 0);
            acc[0][3] = __builtin_amdgcn_mfma_f32_32x32x16_bf16(a[0][kh], b3, acc[0][3], 0, 0, 0);
            acc[1][0] = __builtin_amdgcn_mfma_f32_32x32x16_bf16(a[1][kh], b0, acc[1][0], 0, 0, 0);
            acc[1][1] = __builtin_amdgcn_mfma_f32_32x32x16_bf16(a[1][kh], b1, acc[1][1], 0, 0, 0);
            acc[1][2] = __builtin_amdgcn_mfma_f32_32x32x16_bf16(a[1][kh], b2, acc[1][2], 0, 0, 0);
            acc[1][3] = __builtin_amdgcn_mfma_f32_32x32x16_bf16(a[1][kh], b3, acc[1][3], 0, 0, 0);
        }
        if (step + 1 < NSTEP) {
#pragma unroll
            for (int kh = 0; kh < 4; ++kh) {
                a[0][kh] = an[0][kh];
                a[1][kh] = an[1][kh];
            }
        }
    }

    // epilogue: bias, bf16 store, per-block GroupNorm partials (group = colgrp)
    float bia[4];
#pragma unroll
    for (int n = 0; n < 4; ++n) bia[n] = bias[n * 32 + l31];
    float s[4] = {}, q[4] = {};
#pragma unroll
    for (int m = 0; m < 2; ++m)
#pragma unroll
        for (int n = 0; n < 4; ++n)
#pragma unroll
            for (int r = 0; r < 16; ++r) {
                int crow = (r & 3) + 8 * (r >> 2) + 4 * khalf;
                int row  = n0 + wid * 64 + m * 32 + crow;
                float v  = acc[m][n][r] + bia[n];
                if (row < NLO) {
                    out[((long)b * NLO + row) * 128 + n * 32 + l31] = f2bf(v);
                    s[n] += v; q[n] += v * v;
                }
            }
#pragma unroll
    for (int n = 0; n < 4; ++n)
#pragma unroll
        for (int off = 32; off > 0; off >>= 1) {
            s[n] += __shfl_down(s[n], off);
            q[n] += __shfl_down(q[n], off);
        }
    if (lane == 0) {
#pragma unroll
        for (int n = 0; n < 4; ++n) { red[wid][n][0] = s[n]; red[wid][n][1] = q[n]; }
    }
    __syncthreads();
    if (tid < 8) {
        int g = tid >> 1, isq = tid & 1;
        float v = red[0][g][isq] + red[1][g][isq] + red[2][g][isq] + red[3][g][isq];
        part[(((long)b * gridDim.x + blockIdx.x) * 4 + g) * 2 + isq] = v;
    }
}

// ---------------------------------------------------------------------------
// 5) Finalize stats -> per (b,c) scale/shift. One block per (b,g).
// ---------------------------------------------------------------------------
__global__ void k_finalize(const float* __restrict__ part, int nblk,
                           const float* __restrict__ w, const float* __restrict__ bb,
                           float* __restrict__ scale, float* __restrict__ shift) {
    const int b = blockIdx.x >> 2, g = blockIdx.x & 3;
    const int tid = threadIdx.x;
    float s = 0.f, ss = 0.f;
    for (int k = tid; k < nblk; k += 256) {
        s  += part[(((long)b * nblk + k) * 4 + g) * 2 + 0];
        ss += part[(((long)b * nblk + k) * 4 + g) * 2 + 1];
    }
#pragma unroll
    for (int off = 32; off > 0; off >>= 1) {
        s += __shfl_down(s, off); ss += __shfl_down(ss, off);
    }
    __shared__ float red[8];
    __shared__ float fin[2];
    const int wave = tid >> 6, lane = tid & 63;
    if (lane == 0) { red[wave * 2] = s; red[wave * 2 + 1] = ss; }
    __syncthreads();
    if (tid == 0) {
        float as = red[0] + red[2] + red[4] + red[6];
        float aq = red[1] + red[3] + red[5] + red[7];
        const float cnt = 32.f * NLO;
        float mu  = as / cnt;
        float var = aq / cnt - mu * mu;
        fin[0] = mu; fin[1] = rsqrtf(var + EPS_GN);
    }
    __syncthreads();
    if (tid < 32) {
        int c = g * 32 + tid;
        float sc = fin[1] * w[c];
        scale[b * 128 + c] = sc;
        shift[b * 128 + c] = bb[c] - fin[0] * sc;
    }
}

// ---------------------------------------------------------------------------
// 6) Elementwise gn+leakyrelu: y (B,NLO,128) bf16 -> yp bf16
// ---------------------------------------------------------------------------
__global__ void k_gnapply(const ushort* __restrict__ y, const float* __restrict__ sc,
                          const float* __restrict__ sh, ushort* __restrict__ yp) {
    long t = (long)blockIdx.x * 256 + threadIdx.x;
    const long total = (long)B_SZ * NLO * 16;
    if (t >= total) return;
    int  c8 = (int)(t & 15);
    long bn = t >> 4;
    int  b  = (int)(bn / NLO);
    short8 v = *(const short8*)&y[bn * 128 + c8 * 8];
    short8 o;
#pragma unroll
    for (int e = 0; e < 8; ++e) {
        int c = c8 * 8 + e;
        float f = bf2f((ushort)v[e]) * sc[b * 128 + c] + sh[b * 128 + c];
        f = fmaxf(f, SLOPE * f);
        o[e] = (short)f2bf(f);
    }
    *(short8*)&yp[bn * 128 + c8 * 8] = o;
}

// ---------------------------------------------------------------------------
// 7) Output: gn2 + leakyrelu + transpose (B,N,128) bf16 -> (B,128,N) f32
// ---------------------------------------------------------------------------
__global__ void k_output(const ushort* __restrict__ y2, const float* __restrict__ scale,
                         const float* __restrict__ shift, float* __restrict__ out) {
    __shared__ float t[32][129];
    const int b   = blockIdx.y;
    const int n0  = blockIdx.x * 32;
    const int tid = threadIdx.x;
    const float* scb = &scale[b * 128];
    const float* shb = &shift[b * 128];
    const int c8 = (tid & 15) * 8;
#pragma unroll
    for (int r = 0; r < 2; ++r) {
        int nn = (tid >> 4) + r * 16;
        int n  = n0 + nn;
        if (n < NLO) {
            short8 v = *(const short8*)&y2[((long)b * NLO + n) * 128 + c8];
#pragma unroll
            for (int e = 0; e < 8; ++e) {
                int c = c8 + e;
                float f = bf2f((ushort)v[e]) * scb[c] + shb[c];
                t[nn][c] = fmaxf(f, SLOPE * f);
            }
        } else {
#pragma unroll
            for (int e = 0; e < 8; ++e) t[nn][c8 + e] = 0.f;
        }
    }
    __syncthreads();
    const int n4 = (tid & 7) * 4;
    const bool full = (n0 + 32) <= NLO;
#pragma unroll
    for (int r = 0; r < 4; ++r) {
        int c = (tid >> 3) + r * 32;
        long o = ((long)b * 128 + c) * NLO + n0 + n4;
        if (full) {
            float2 v0 = make_float2(t[n4][c], t[n4 + 1][c]);
            float2 v1 = make_float2(t[n4 + 2][c], t[n4 + 3][c]);
            *(float2*)&out[o]     = v0;
            *(float2*)&out[o + 2] = v1;
        } else {
            for (int e = 0; e < 4; ++e)
                if (n0 + n4 + e < NLO) out[o + e] = t[n4 + e][c];
        }
    }
}

// ---------------------------------------------------------------------------
// Launch
// ---------------------------------------------------------------------------
extern "C" void kernel_launch(void* const* d_in, const int* in_sizes, int n_in,
                              void* d_out, int out_size, void* d_ws, size_t ws_size,
                              hipStream_t stream) {
    const float* x   = (const float*)d_in[0];
    const int*   pn  = (const int*)d_in[1];
    const int*   cn  = (const int*)d_in[2];
    const float* W1  = (const float*)d_in[3];
    const float* b1  = (const float*)d_in[4];
    const float* g1w = (const float*)d_in[5];
    const float* g1b = (const float*)d_in[6];
    const float* W2  = (const float*)d_in[7];
    const float* b2  = (const float*)d_in[8];
    const float* g2w = (const float*)d_in[9];
    const float* g2b = (const float*)d_in[10];
    float* out = (float*)d_out;
    char*  base = (char*)d_ws;

    ushort* xT  = (ushort*)(base + 0);           // 83,887,104 B
    ushort* y1  = (ushort*)(base + 0);           // reuse (xT dead after pool)
    ushort* y1p = (ushort*)(base + 44000000);
    ushort* h1  = (ushort*)(base + 88000000);
    ushort* y2  = (ushort*)(base + 110000000);
    ushort* wb1 = (ushort*)(base + 152000000);
    ushort* wb2 = (ushort*)(base + 152200000);
    float*  p1  = (float*)(base + 152500000);
    float*  p2  = (float*)(base + 152600000);
    float*  sc1 = (float*)(base + 152700000);
    float*  sh1 = sc1 + 512;
    float*  sc2 = (float*)(base + 152710000);
    float*  sh2 = sc2 + 512;

    const int NBLK = (NLO + 255) / 256;  // 161 conv blocks per batch

    k_transpose_x<<<dim3((NHI + 63) / 64, B_SZ), 256, 0, stream>>>(x, xT);
    k_prep_w<<<(448 * 128 + 255) / 256, 256, 0, stream>>>(W1, wb1, 448);
    k_prep_w<<<(896 * 128 + 255) / 256, 256, 0, stream>>>(W2, wb2, 896);
    k_pool<<<(int)(((long)B_SZ * NLO * 8 + 255) / 256), 256, 0, stream>>>(xT, pn, h1);
    k_conv_mfma<64><<<dim3(NBLK, B_SZ), 256, 0, stream>>>(h1, cn, wb1, b1, y1, p1);
    k_finalize<<<16, 256, 0, stream>>>(p1, NBLK, g1w, g1b, sc1, sh1);
    k_gnapply<<<(int)(((long)B_SZ * NLO * 16 + 255) / 256), 256, 0, stream>>>(y1, sc1, sh1, y1p);
    k_conv_mfma<128><<<dim3(NBLK, B_SZ), 256, 0, stream>>>(y1p, cn, wb2, b2, y2, p2);
    k_finalize<<<16, 256, 0, stream>>>(p2, NBLK, g2w, g2b, sc2, sh2);
    k_output<<<dim3((NLO + 31) / 32, B_SZ), 256, 0, stream>>>(y2, sc2, sh2, out);
}